// Round 1
// baseline (1795.407 us; speedup 1.0000x reference)
//
#include <hip/hip_runtime.h>
#include <math.h>

// Problem constants (from reference): B=128, O=32, I=2048, Do=16, Di=8
#define B_N 128
#define O_N 32
#define I_N 2048
#define DO_N 16
#define DI_N 8

constexpr long BOI = (long)B_N * O_N * I_N;          // 8388608
constexpr long OUT_ELEMS = (long)B_N * O_N * DO_N;   // 65536
constexpr long COUPS_OFF = OUT_ELEMS;                // coups[3,B,O,I] after out
constexpr long BETAS_OFF = OUT_ELEMS + 3 * BOI;      // betas[3,B,O,I] after coups

// pass-kernel geometry
#define WAVES 8
#define THREADS (WAVES * 64)            // 512
#define NBS 2                           // b-slots per thread
#define B_PER_BLOCK (WAVES * 2 * NBS)   // 32 b's per block
#define BGROUPS (B_N / B_PER_BLOCK)     // 4
#define ICHUNK 32
#define IBLOCKS (I_N / ICHUNK)          // 64

// ---------------------------------------------------------------------------
// K0: fill constant outputs (coups[0]=1/32, betas[0]=0) and zero ws buffers
// ---------------------------------------------------------------------------
__global__ void fill_kernel(float* __restrict__ out, float* __restrict__ ws) {
    const float4 vc = make_float4(0.03125f, 0.03125f, 0.03125f, 0.03125f);
    const float4 vz = make_float4(0.f, 0.f, 0.f, 0.f);
    long tid = (long)blockIdx.x * blockDim.x + threadIdx.x;
    long stride = (long)gridDim.x * blockDim.x;
    float4* c0 = (float4*)(out + COUPS_OFF);  // coups[0]
    float4* b0 = (float4*)(out + BETAS_OFF);  // betas[0]
    float4* w4 = (float4*)ws;                 // sacc0,sacc1,sacc2,ocsum
    const long n = BOI / 4;                   // 2097152 float4 per region
    for (long idx = tid; idx < n; idx += stride) { c0[idx] = vc; b0[idx] = vz; }
    const long nw = OUT_ELEMS;                // 4*OUT_ELEMS floats / 4
    for (long idx = tid; idx < nw; idx += stride) w4[idx] = vz;
}

// ---------------------------------------------------------------------------
// Pass kernel: recomputes uhat on the fly.
// PASS==0: sacc += (1/32) * uhat (c uniform; betas/coups handled by fill)
// PASS>=1: bv = dot(ocsum, uhat); c = softmax_o(bv); write betas/coups[PASS];
//          sacc += c * uhat
// Thread map: lane = bh*32 + o; each thread owns NBS b-slots.
// ---------------------------------------------------------------------------
template<int PASS>
__global__ __launch_bounds__(THREADS)
void pass_kernel(const float* __restrict__ incaps,
                 const float* __restrict__ weight,
                 const float* __restrict__ ocsum,
                 float* __restrict__ sacc,
                 float* __restrict__ dout)
{
    const int lane = threadIdx.x & 63;
    const int wv   = threadIdx.x >> 6;
    const int o    = lane & 31;
    const int bh   = lane >> 5;
    const int ib   = blockIdx.x;           // i-chunk  [0, IBLOCKS)
    const int bg   = blockIdx.y;           // b-group  [0, BGROUPS)

    int bidx[NBS];
#pragma unroll
    for (int j = 0; j < NBS; ++j)
        bidx[j] = bg * B_PER_BLOCK + wv * (2 * NBS) + 2 * j + bh;

    // cumulative outcaps sum for this (b,o) — fixed for whole kernel
    float oc[NBS][DO_N];
    if (PASS > 0) {
#pragma unroll
        for (int j = 0; j < NBS; ++j) {
            const float4* p = (const float4*)(ocsum + ((long)bidx[j] * O_N + o) * DO_N);
#pragma unroll
            for (int q = 0; q < 4; ++q) {
                float4 v = p[q];
                oc[j][4*q+0] = v.x; oc[j][4*q+1] = v.y;
                oc[j][4*q+2] = v.z; oc[j][4*q+3] = v.w;
            }
        }
    }

    float sa[NBS][DO_N];
#pragma unroll
    for (int j = 0; j < NBS; ++j)
#pragma unroll
        for (int d = 0; d < DO_N; ++d) sa[j][d] = 0.f;

    const int i0 = ib * ICHUNK;
    for (int ii = 0; ii < ICHUNK; ++ii) {
        const int i = i0 + ii;

        // incaps[b, i, 0..7]
        float x[NBS][DI_N];
#pragma unroll
        for (int j = 0; j < NBS; ++j) {
            const float4* p = (const float4*)(incaps + ((long)bidx[j] * I_N + i) * DI_N);
            float4 a = p[0], b = p[1];
            x[j][0]=a.x; x[j][1]=a.y; x[j][2]=a.z; x[j][3]=a.w;
            x[j][4]=b.x; x[j][5]=b.y; x[j][6]=b.z; x[j][7]=b.w;
        }

        // uhat[b,o,i,d] = sum_k weight[o,i,d,k] * incaps[b,i,k]
        float uh[NBS][DO_N];
        const float4* wp = (const float4*)(weight + ((long)o * I_N + i) * (DO_N * DI_N));
#pragma unroll
        for (int d = 0; d < DO_N; ++d) {
            float4 wa = wp[2*d], wb = wp[2*d+1];
#pragma unroll
            for (int j = 0; j < NBS; ++j) {
                uh[j][d] = wa.x*x[j][0] + wa.y*x[j][1] + wa.z*x[j][2] + wa.w*x[j][3]
                         + wb.x*x[j][4] + wb.y*x[j][5] + wb.z*x[j][6] + wb.w*x[j][7];
            }
        }

        if (PASS == 0) {
#pragma unroll
            for (int j = 0; j < NBS; ++j)
#pragma unroll
                for (int d = 0; d < DO_N; ++d) sa[j][d] += uh[j][d];
        } else {
#pragma unroll
            for (int j = 0; j < NBS; ++j) {
                float bv = 0.f;
#pragma unroll
                for (int d = 0; d < DO_N; ++d) bv += oc[j][d] * uh[j][d];

                // softmax over o (axis=1) within the 32-lane group
                float m = bv;
#pragma unroll
                for (int msk = 16; msk >= 1; msk >>= 1)
                    m = fmaxf(m, __shfl_xor(m, msk));
                float e = expf(bv - m);
                float s = e;
#pragma unroll
                for (int msk = 16; msk >= 1; msk >>= 1)
                    s += __shfl_xor(s, msk);
                float c = e / s;

                const long ridx = ((long)bidx[j] * O_N + o) * I_N + i;
                dout[COUPS_OFF + (long)PASS * BOI + ridx] = c;
                dout[BETAS_OFF + (long)PASS * BOI + ridx] = bv;

#pragma unroll
                for (int d = 0; d < DO_N; ++d) sa[j][d] += c * uh[j][d];
            }
        }
    }

    const float scale = (PASS == 0) ? (1.0f / 32.0f) : 1.0f;
#pragma unroll
    for (int j = 0; j < NBS; ++j)
#pragma unroll
        for (int d = 0; d < DO_N; ++d)
            atomicAdd(&sacc[((long)bidx[j] * O_N + o) * DO_N + d], sa[j][d] * scale);
}

// ---------------------------------------------------------------------------
// Squash: outcaps = squash(sacc); either accumulate into ocsum (mid passes)
// or write final out (last pass).
// ---------------------------------------------------------------------------
template<bool FINAL>
__global__ void squash_kernel(const float* __restrict__ sacc,
                              float* __restrict__ ocsum,
                              float* __restrict__ dout)
{
    int t = blockIdx.x * blockDim.x + threadIdx.x;   // (b*O + o)
    if (t >= B_N * O_N) return;
    float v[DO_N]; float n2 = 0.f;
    const float4* p = (const float4*)(sacc + (long)t * DO_N);
#pragma unroll
    for (int q = 0; q < 4; ++q) {
        float4 a = p[q];
        v[4*q+0]=a.x; v[4*q+1]=a.y; v[4*q+2]=a.z; v[4*q+3]=a.w;
    }
#pragma unroll
    for (int d = 0; d < DO_N; ++d) n2 += v[d]*v[d];
    float n = sqrtf(n2);
    float scale = n2 / ((1.f + n2) * (n + 1e-8f));
    if (FINAL) {
#pragma unroll
        for (int d = 0; d < DO_N; ++d) dout[(long)t * DO_N + d] = scale * v[d];
    } else {
#pragma unroll
        for (int d = 0; d < DO_N; ++d) ocsum[(long)t * DO_N + d] += scale * v[d];
    }
}

// ---------------------------------------------------------------------------
extern "C" void kernel_launch(void* const* d_in, const int* in_sizes, int n_in,
                              void* d_out, int out_size, void* d_ws, size_t ws_size,
                              hipStream_t stream)
{
    const float* incaps = (const float*)d_in[0];   // [B, I, Di] f32
    const float* weight = (const float*)d_in[1];   // [O, I, Do, Di] f32
    float* out = (float*)d_out;
    float* ws  = (float*)d_ws;

    float* sacc0 = ws;                    // [B,O,16]
    float* sacc1 = ws + OUT_ELEMS;
    float* sacc2 = ws + 2 * OUT_ELEMS;
    float* ocsum = ws + 3 * OUT_ELEMS;    // cumulative outcaps

    fill_kernel<<<1024, 256, 0, stream>>>(out, ws);

    dim3 pg(IBLOCKS, BGROUPS);
    pass_kernel<0><<<pg, THREADS, 0, stream>>>(incaps, weight, ocsum, sacc0, out);
    squash_kernel<false><<<(B_N * O_N + 255) / 256, 256, 0, stream>>>(sacc0, ocsum, nullptr);
    pass_kernel<1><<<pg, THREADS, 0, stream>>>(incaps, weight, ocsum, sacc1, out);
    squash_kernel<false><<<(B_N * O_N + 255) / 256, 256, 0, stream>>>(sacc1, ocsum, nullptr);
    pass_kernel<2><<<pg, THREADS, 0, stream>>>(incaps, weight, ocsum, sacc2, out);
    squash_kernel<true><<<(B_N * O_N + 255) / 256, 256, 0, stream>>>(sacc2, ocsum, out);
}